// Round 11
// baseline (444.607 us; speedup 1.0000x reference)
//
#include <hip/hip_runtime.h>

// ---------------- problem constants ----------------
constexpr int Bn = 8, Ln = 1024, Dn = 128, Pn = 8, Wn = 2048;
constexpr float FTc = 0.1f;
constexpr int BLDc = Bn * Ln * Dn;   // 1048576
constexpr int BWDc = Bn * Wn * Dn;   // 2097152
constexpr int IDM = 1 << 28;         // identity row-map modulus

struct __align__(16) F4 { float v[4]; };

typedef __attribute__((ext_vector_type(8))) __bf16 bf16x8;
typedef __attribute__((ext_vector_type(8))) short short8v;
typedef __attribute__((ext_vector_type(4))) short short4v;
typedef __attribute__((ext_vector_type(4))) float f32x4;

static __device__ __forceinline__ float sigm(float x) { return 1.f / (1.f + expf(-x)); }

// f32 -> bf16 bits, round-to-nearest-even
static __device__ __forceinline__ short f2bf(float f) {
    unsigned u = __builtin_bit_cast(unsigned, f);
    unsigned r = (u + 0x7FFFu + ((u >> 16) & 1u)) >> 16;
    return (short)r;
}
static __device__ __forceinline__ float bf2f(short s) {
    return __builtin_bit_cast(float, ((unsigned)(unsigned short)s) << 16);
}

// ---------------- MFMA linear:  Y = act( X @ W^T + b ) ----------------
template<int NSRC, int ACT, int OUT, int BM>
__global__ __launch_bounds__(256)
void linmfma(const short* __restrict__ x0, const short* __restrict__ x1,
             const short* __restrict__ x2, const short* __restrict__ x3,
             const float* __restrict__ Wt, const float* __restrict__ bias,
             float* __restrict__ Y, short* __restrict__ Yh,
             int in_mod, int in_stride, int in_off,
             int out_mod, int out_stride, int out_off,
             const float* __restrict__ fbuf, const float* __restrict__ bbuf)
{
    constexpr int K = NSRC * 128;
    constexpr int NKB = K / 64;
    constexpr int WRr = BM / 16;
    constexpr int WC = 4 / WRr;
    constexpr int NF = 8 / WC;
    constexpr int CPW = 128 / WC;
    __shared__ short sX[BM * 72];
    __shared__ short sW[128 * 72];

    const int tid = threadIdx.x;
    const int wave = tid >> 6, lane = tid & 63;
    const int l15 = lane & 15, l4 = lane >> 4;
    const int rg = wave % WRr, cg = wave / WRr;
    const int n0 = blockIdx.x * BM;
    const int inRow0  = (n0 / in_mod)  * in_stride  + (n0 % in_mod)  + in_off;
    const int outRow0 = (n0 / out_mod) * out_stride + (n0 % out_mod) + out_off;

    f32x4 acc[NF];
    #pragma unroll
    for (int nf = 0; nf < NF; ++nf) acc[nf] = (f32x4){0.f, 0.f, 0.f, 0.f};

    const int xrow = tid >> 3, xk8 = (tid & 7) * 8;

    for (int kb = 0; kb < NKB; ++kb) {
        const int k0 = kb * 64;
        __syncthreads();
        if (tid < BM * 8) {
            const short* __restrict__ src;
            { int s = k0 >> 7; src = (s == 0) ? x0 : (s == 1) ? x1 : (s == 2) ? x2 : x3; }
            const int koff = k0 & 127;
            *(short8v*)&sX[xrow * 72 + xk8] =
                *(const short8v*)(src + (size_t)(inRow0 + xrow) * 128 + koff + xk8);
        }
        #pragma unroll
        for (int it = 0; it < 4; ++it) {
            int idx = tid + it * 256;
            int m = idx >> 3, k8 = (idx & 7) * 8;
            const float* pw = Wt + (size_t)m * K + k0 + k8;
            F4 v0 = *(const F4*)pw, v1 = *(const F4*)(pw + 4);
            short8v sv;
            #pragma unroll
            for (int e = 0; e < 4; ++e) { sv[e] = f2bf(v0.v[e]); sv[4 + e] = f2bf(v1.v[e]); }
            *(short8v*)&sW[m * 72 + k8] = sv;
        }
        __syncthreads();
        #pragma unroll
        for (int ksub = 0; ksub < 2; ++ksub) {
            bf16x8 af = *(const bf16x8*)&sX[(rg * 16 + l15) * 72 + ksub * 32 + l4 * 8];
            #pragma unroll
            for (int nf = 0; nf < NF; ++nf) {
                bf16x8 bv = *(const bf16x8*)&sW[(cg * CPW + nf * 16 + l15) * 72 + ksub * 32 + l4 * 8];
                acc[nf] = __builtin_amdgcn_mfma_f32_16x16x32_bf16(af, bv, acc[nf], 0, 0, 0);
            }
        }
    }

    const int r0 = rg * 16 + l4 * 4;
    #pragma unroll
    for (int nf = 0; nf < NF; ++nf) {
        int col = cg * CPW + nf * 16 + l15;
        float bs = bias[col];
        #pragma unroll
        for (int r = 0; r < 4; ++r) {
            int row = outRow0 + r0 + r;
            float v = acc[nf][r] + bs;
            if constexpr (ACT == 1) v = fmaxf(v, 0.f);
            if constexpr (ACT == 2) v = sigm(v);
            if constexpr (ACT == 3) {
                float f = fbuf[(size_t)row * 128 + col];
                float base = bbuf[(size_t)row * 128 + col];
                v = fmaxf(f, FTc) * base + (1.f - f) * fmaxf(v, 0.f);
            }
            if constexpr (OUT & 1) Y[(size_t)row * 128 + col] = v;
            if constexpr (OUT & 2) Yh[(size_t)row * 128 + col] = f2bf(v);
        }
    }
}

// ---------------- dual-output X producer ----------------
// Xk = x @ W0^T + b0, Xs = x @ W1^T + b1; both written in blocked bf16 layout
// (chunk b*64+kb32 = [col 0..127][kin 0..31], 4096 shorts). Identity row map.
__global__ __launch_bounds__(256)
void lin2x(const short* __restrict__ x0,
           const float* __restrict__ W0, const float* __restrict__ b0v,
           const float* __restrict__ W1, const float* __restrict__ b1v,
           short* __restrict__ Xout0, short* __restrict__ Xout1)
{
    __shared__ short sX[32 * 72];
    __shared__ short sW[2][128 * 72];
    const int tid = threadIdx.x;
    const int wave = tid >> 6, lane = tid & 63;
    const int l15 = lane & 15, l4 = lane >> 4;
    const int rg = wave & 1, cg = wave >> 1;
    const int n0 = blockIdx.x * 32;

    f32x4 acc[2][4];
    #pragma unroll
    for (int o = 0; o < 2; ++o) {
        #pragma unroll
        for (int nf = 0; nf < 4; ++nf) {
            acc[o][nf] = (f32x4){0.f, 0.f, 0.f, 0.f};
        }
    }

    const int xrow = tid >> 3, xk8 = (tid & 7) * 8;

    #pragma unroll
    for (int kb = 0; kb < 2; ++kb) {
        const int k0 = kb * 64;
        __syncthreads();
        *(short8v*)&sX[xrow * 72 + xk8] =
            *(const short8v*)(x0 + (size_t)(n0 + xrow) * 128 + k0 + xk8);
        #pragma unroll
        for (int o = 0; o < 2; ++o) {
            const float* __restrict__ Wt = o ? W1 : W0;
            #pragma unroll
            for (int it = 0; it < 4; ++it) {
                int idx = tid + it * 256;
                int m = idx >> 3, k8 = (idx & 7) * 8;
                const float* pw = Wt + (size_t)m * 128 + k0 + k8;
                F4 v0 = *(const F4*)pw, v1 = *(const F4*)(pw + 4);
                short8v sv;
                #pragma unroll
                for (int e = 0; e < 4; ++e) { sv[e] = f2bf(v0.v[e]); sv[4 + e] = f2bf(v1.v[e]); }
                *(short8v*)&sW[o][m * 72 + k8] = sv;
            }
        }
        __syncthreads();
        #pragma unroll
        for (int ksub = 0; ksub < 2; ++ksub) {
            bf16x8 af = *(const bf16x8*)&sX[(rg * 16 + l15) * 72 + ksub * 32 + l4 * 8];
            #pragma unroll
            for (int o = 0; o < 2; ++o) {
                #pragma unroll
                for (int nf = 0; nf < 4; ++nf) {
                    bf16x8 bv = *(const bf16x8*)&sW[o][(cg * 64 + nf * 16 + l15) * 72 + ksub * 32 + l4 * 8];
                    acc[o][nf] = __builtin_amdgcn_mfma_f32_16x16x32_bf16(af, bv, acc[o][nf], 0, 0, 0);
                }
            }
        }
    }

    const int r0 = rg * 16 + l4 * 4;
    __syncthreads();
    #pragma unroll
    for (int o = 0; o < 2; ++o) {
        const float* bv = o ? b1v : b0v;
        #pragma unroll
        for (int nf = 0; nf < 4; ++nf) {
            int col = cg * 64 + nf * 16 + l15;
            float bs = bv[col];
            #pragma unroll
            for (int r = 0; r < 4; ++r) {
                sW[o][col * 40 + r0 + r] = f2bf(acc[o][nf][r] + bs);
            }
        }
    }
    __syncthreads();
    const int bb = n0 >> 11, kbo = (n0 & 2047) >> 5;
    #pragma unroll
    for (int o = 0; o < 2; ++o) {
        short* __restrict__ dst = (o ? Xout1 : Xout0) + ((size_t)(bb * 64 + kbo)) * 4096;
        #pragma unroll
        for (int it = 0; it < 2; ++it) {
            int t2 = tid + it * 256;
            int col = t2 >> 2, k8 = (t2 & 3) * 8;
            *(short8v*)(dst + (size_t)t2 * 8) = *(const short8v*)&sW[o][col * 40 + k8];
        }
    }
}

// ---------------- barrier-free split-K MFMA gemm partial ----------------
// No LDS, no __syncthreads in the K-loop: each wave owns 16 rows x 128 cols
// of one K-window. A loaded global->reg in MFMA lane layout; B read directly
// from blocked Xblk (coalesced 1KB/instr, L1-hot: 4 waves/block share chunks).
// Compiler emits counted vmcnt per use -> loads stay in flight (no drain).
// AMODE: 0 = A0 f32; 1 = A0*A1 f32 inline; 2 = Abf bf16 row-major.
// WRA: write bf16-converted A through to Awr for pass-2 reuse.
// Grid (NI/64, B, KCH); 256 thr = 4 waves x 16 rows.
template<int AMODE, bool WRA>
__global__ __launch_bounds__(256)
void mfma_gemm6(const float* __restrict__ A0, const float* __restrict__ A1,
                const short* __restrict__ Abf, short* __restrict__ Awr,
                const short* __restrict__ Xblk, short* __restrict__ part,
                int NI, int KJ, int KL, int xkb0)
{
    const int tid = threadIdx.x;
    const int wave = tid >> 6, lane = tid & 63;
    const int l15 = lane & 15, l4 = lane >> 4;
    const int b = blockIdx.y, kc = blockIdx.z;
    const int i0 = blockIdx.x * 64 + wave * 16;
    const size_t aRow = ((size_t)b * NI + i0 + l15) * KJ + (size_t)kc * KL;
    const int nks = KL >> 5;                    // 32-k steps
    const int cb0 = b * 64 + xkb0 + ((kc * KL) >> 5);
    const int lko = l4 * 8;

    f32x4 acc[8];
    #pragma unroll
    for (int nf = 0; nf < 8; ++nf) acc[nf] = (f32x4){0.f, 0.f, 0.f, 0.f};

    #pragma unroll 4
    for (int ks = 0; ks < nks; ++ks) {
        const size_t ao = aRow + ks * 32 + lko;
        bf16x8 af;
        if constexpr (AMODE == 2) {
            af = *(const bf16x8*)(Abf + ao);
        } else {
            F4 v0 = *(const F4*)(A0 + ao);
            F4 v1 = *(const F4*)(A0 + ao + 4);
            if constexpr (AMODE == 1) {
                F4 w0 = *(const F4*)(A1 + ao);
                F4 w1 = *(const F4*)(A1 + ao + 4);
                #pragma unroll
                for (int e = 0; e < 4; ++e) { v0.v[e] *= w0.v[e]; v1.v[e] *= w1.v[e]; }
            }
            short8v sv;
            #pragma unroll
            for (int e = 0; e < 4; ++e) { sv[e] = f2bf(v0.v[e]); sv[4 + e] = f2bf(v1.v[e]); }
            if constexpr (WRA) *(short8v*)(Awr + ao) = sv;
            af = __builtin_bit_cast(bf16x8, sv);
        }
        const short* bp = Xblk + (size_t)(cb0 + ks) * 4096 + lko;
        #pragma unroll
        for (int nf = 0; nf < 8; ++nf) {
            bf16x8 bv = *(const bf16x8*)(bp + (nf * 16 + l15) * 32);
            acc[nf] = __builtin_amdgcn_mfma_f32_16x16x32_bf16(af, bv, acc[nf], 0, 0, 0);
        }
    }

    const size_t pbase = (((size_t)kc * Bn + b) * NI + i0 + l4 * 4) * 128;
    #pragma unroll
    for (int nf = 0; nf < 8; ++nf) {
        #pragma unroll
        for (int r = 0; r < 4; ++r) {
            part[pbase + (size_t)r * 128 + nf * 16 + l15] = f2bf(acc[nf][r]);
        }
    }
}

// ---- finalize: sum KCH bf16 partials, row-l2 normalize, write bf16 Yh ------
__global__ void k_gemm_finh(const short* __restrict__ part, short* __restrict__ Yh,
                            int NI, int KCH, int ybs, int yoff)
{
    int row = blockIdx.x; int b = row / NI; int i = row - b * NI;
    int h = threadIdx.x;
    float s = 0.f;
    for (int kc = 0; kc < KCH; ++kc)
        s += bf2f(part[(((size_t)kc * Bn + b) * NI + i) * 128 + h]);
    __shared__ float red[128];
    red[h] = s * s; __syncthreads();
    for (int st = 64; st > 0; st >>= 1) { if (h < st) red[h] += red[h + st]; __syncthreads(); }
    Yh[(size_t)(b * ybs + yoff + i) * 128 + h] = f2bf(s / (sqrtf(red[0]) + 1e-30f));
}

// ---------------- small kernels ----------------
__global__ void k_allword(const float* __restrict__ s0, const float* __restrict__ s1,
                          float* __restrict__ aw, short* __restrict__ awh)
{
    int i = blockIdx.x * 256 + threadIdx.x;
    int b = i / (Ln * Dn / 4);
    F4 v0 = ((const F4*)s0)[i];
    F4 v1 = ((const F4*)s1)[i];
    int d0 = i + b * (Ln * Dn / 4);
    int d1 = i + (b + 1) * (Ln * Dn / 4);
    ((F4*)aw)[d0] = v0;
    ((F4*)aw)[d1] = v1;
    short4v h0, h1;
    #pragma unroll
    for (int e = 0; e < 4; ++e) { h0[e] = f2bf(v0.v[e]); h1[e] = f2bf(v1.v[e]); }
    ((short4v*)awh)[d0] = h0;
    ((short4v*)awh)[d1] = h1;
}

__global__ void k_goalg(const float* __restrict__ node, const float* __restrict__ Wg,
                        const float* __restrict__ bg, float* __restrict__ gvec,
                        float* __restrict__ gnorm)
{
    int b = blockIdx.x, h = threadIdx.x;
    float s = bg[h];
    for (int k = 0; k < 128; ++k) s += node[b * 128 + k] * Wg[h * 128 + k];
    gvec[b * 128 + h] = s;
    __shared__ float red[128];
    red[h] = s * s; __syncthreads();
    for (int st = 64; st > 0; st >>= 1) { if (h < st) red[h] += red[h + st]; __syncthreads(); }
    if (h == 0) gnorm[b] = sqrtf(red[0]);
}

__global__ void k_wordg(const float* __restrict__ gvec, const float* __restrict__ gnorm,
                        const float* __restrict__ gw, short* __restrict__ wgh)
{
    int row = blockIdx.x; int b = row >> 11; int h = threadIdx.x;
    float s = gw[row];
    float coef = s / (s * gnorm[b] + 1e-30f);
    wgh[(size_t)row * 128 + h] = f2bf(gvec[b * 128 + h] * coef);
}

// ---- word_op: split-K partial reduction over W ----
__global__ __launch_bounds__(256)
void k_wordop_part(const float* __restrict__ wes, const float* __restrict__ wopr,
                   const float* __restrict__ Yl, float* __restrict__ part,
                   float* __restrict__ pcnt)
{
    int c = blockIdx.x, b = blockIdx.y;
    int w0 = c * 32;
    __shared__ float sc[32][8];
    int tid = threadIdx.x;
    {
        int w = tid >> 3, p = tid & 7;
        sc[w][p] = wes[b * Wn + w0 + w] * wopr[(size_t)(b * Wn + w0 + w) * Pn + p];
    }
    __syncthreads();
    if (tid < 8) {
        float n = 0.f;
        for (int w = 0; w < 32; ++w) n += (sc[w][tid] != 0.f) ? 1.f : 0.f;
        pcnt[(c * 8 + b) * 8 + tid] = n;
    }
    int d = tid & 127, g = tid >> 7;
    float acc[4] = {};
    for (int w = 0; w < 32; ++w) {
        float y = Yl[(size_t)(b * Wn + w0 + w) * 128 + d];
        #pragma unroll
        for (int q = 0; q < 4; ++q) acc[q] += sc[w][g * 4 + q] * y;
    }
    #pragma unroll
    for (int q = 0; q < 4; ++q)
        part[(((size_t)c * 8 + b) * 8 + g * 4 + q) * 128 + d] = acc[q];
}

__global__ void k_wordop_fin(const float* __restrict__ part, const float* __restrict__ pcnt,
                             float* __restrict__ outp)
{
    int bp = blockIdx.x;
    int b = bp >> 3, p = bp & 7;
    int d = threadIdx.x;
    float s = 0.f, n = 0.f;
    for (int c = 0; c < 64; ++c) s += part[(((size_t)c * 8 + b) * 8 + p) * 128 + d];
    for (int c = 0; c < 64; ++c) n += pcnt[(c * 8 + b) * 8 + p];
    outp[(size_t)bp * 128 + d] = s / (n + 1e-30f);
}

__global__ void k_opemb(const float* __restrict__ oein, const float* __restrict__ wop,
                        const float* __restrict__ W2, const float* __restrict__ b2,
                        const float* __restrict__ Wlo, const float* __restrict__ blo,
                        float* __restrict__ opembN, float* __restrict__ out2)
{
    int bp = blockIdx.x; int h = threadIdx.x;
    const float* oe = oein + (size_t)bp * 128;
    const float* wo = wop + (size_t)bp * 128;
    float s = b2[h], lo = blo[h];
    for (int k = 0; k < 128; ++k) {
        s += oe[k] * W2[h * 256 + k];
        s += wo[k] * W2[h * 256 + 128 + k];
        lo += wo[k] * Wlo[h * 128 + k];
    }
    float f = sigm(s);
    float v = fmaxf(f, FTc) * oe[h] + (1.f - f) * fmaxf(lo, 0.f);
    opembN[bp * 128 + h] = v;
    out2[bp * 128 + h] = v;
}

__global__ void k_opn(const float* __restrict__ opembN, float* __restrict__ opn)
{
    __shared__ float red[128];
    int bp = blockIdx.x, h = threadIdx.x;
    float v = opembN[bp * 128 + h];
    red[h] = v * v; __syncthreads();
    for (int s = 64; s > 0; s >>= 1) { if (h < s) red[h] += red[h + s]; __syncthreads(); }
    opn[bp * 128 + h] = v / (sqrtf(red[0]) + 1e-30f);
}

__global__ void k_cfrel(const float* __restrict__ opn, const float* __restrict__ Wf,
                        const float* __restrict__ bf, const float* __restrict__ Wr,
                        const float* __restrict__ br, float* __restrict__ cf,
                        float* __restrict__ crel)
{
    int bp = blockIdx.x; int b = bp >> 3, p = bp & 7;
    int t = threadIdx.x;
    float sf = 0.f, sr = 0.f;
    for (int k = t; k < 1024; k += 256) {
        float o = opn[b * 1024 + k];
        sf += o * Wf[p * 1152 + 128 + k];
        sr += o * Wr[p * 1152 + 128 + k];
    }
    __shared__ float rf[256], rr[256];
    rf[t] = sf; rr[t] = sr; __syncthreads();
    for (int s = 128; s > 0; s >>= 1) {
        if (t < s) { rf[t] += rf[t + s]; rr[t] += rr[t + s]; }
        __syncthreads();
    }
    if (t == 0) { cf[bp] = rf[0] + bf[p]; crel[bp] = rr[0] + br[p]; }
}

__global__ __launch_bounds__(256)
void k_fgrel(const float* __restrict__ wupd, const float* __restrict__ Wf,
             const float* __restrict__ Wr, const float* __restrict__ cf,
             const float* __restrict__ crel, float* __restrict__ fgb,
             float* __restrict__ relb)
{
    __shared__ float sXr[32 * 132];
    __shared__ float sinv[32];
    int tid = threadIdx.x;
    int n0 = blockIdx.x * 32;
    for (int l = tid; l < 4096; l += 256) {
        int r = l >> 7, h = l & 127;
        sXr[r * 132 + h] = wupd[(size_t)(n0 + r) * 128 + h];
    }
    __syncthreads();
    if (tid < 32) {
        float s = 0.f;
        for (int h = 0; h < 128; ++h) { float v = sXr[tid * 132 + h]; s += v * v; }
        sinv[tid] = 1.f / (sqrtf(s) + 1e-30f);
    }
    __syncthreads();
    int r = tid >> 3, p = tid & 7;
    int n = n0 + r; int b = n >> 11;
    float af = 0.f, ar = 0.f, inv = sinv[r];
    for (int d = 0; d < 128; ++d) {
        float x = sXr[r * 132 + d] * inv;
        af += x * Wf[p * 1152 + d];
        ar += x * Wr[p * 1152 + d];
    }
    float f = sigm(af + cf[b * 8 + p]);
    fgb[(size_t)n * 8 + p] = fmaxf(f, FTc);
    relb[(size_t)n * 8 + p] = ar + crel[b * 8 + p];
}

__global__ void k_wopnew(const float* __restrict__ wopr, const float* __restrict__ fgb,
                         const float* __restrict__ relb, const float* __restrict__ Wu,
                         const float* __restrict__ bu, float* __restrict__ wopn)
{
    int row = blockIdx.x * 256 + threadIdx.x;
    float t16[16];
    #pragma unroll
    for (int p = 0; p < 8; ++p) t16[p] = wopr[(size_t)row * 8 + p];
    #pragma unroll
    for (int p = 0; p < 8; ++p) t16[8 + p] = relb[(size_t)row * 8 + p];
    float u[8]; float m = -1e30f;
    #pragma unroll
    for (int p = 0; p < 8; ++p) {
        float s = bu[p];
        #pragma unroll
        for (int q = 0; q < 16; ++q) s += Wu[p * 16 + q] * t16[q];
        s = fmaxf(s, 0.f); u[p] = s; m = fmaxf(m, s);
    }
    float tot = 0.f;
    #pragma unroll
    for (int p = 0; p < 8; ++p) { u[p] = expf(u[p] - m); tot += u[p]; }
    float itot = 1.f / tot;
    #pragma unroll
    for (int p = 0; p < 8; ++p) {
        float f = fgb[(size_t)row * 8 + p];
        wopn[(size_t)row * 8 + p] = f * t16[p] + (1.f - f) * u[p] * itot;
    }
}

__global__ void k_opw(const float* __restrict__ opembN, const float* __restrict__ Wo,
                      const float* __restrict__ bo, float* __restrict__ opw)
{
    int bp = blockIdx.x, h = threadIdx.x;
    float s = bo[h];
    for (int d = 0; d < 128; ++d) s += opembN[bp * 128 + d] * Wo[h * 128 + d];
    opw[bp * 128 + h] = s;
}

__global__ void k_wordo(const float* __restrict__ wopn, const float* __restrict__ opw,
                        short* __restrict__ woh)
{
    int row = blockIdx.x; int b = row >> 11; int h = threadIdx.x;
    float c[8];
    #pragma unroll
    for (int p = 0; p < 8; ++p) c[p] = wopn[(size_t)row * 8 + p];
    float v = 0.f;
    #pragma unroll
    for (int p = 0; p < 8; ++p) v += c[p] * opw[(b * 8 + p) * 128 + h];
    __shared__ float red[128];
    red[h] = v * v; __syncthreads();
    for (int s = 64; s > 0; s >>= 1) { if (h < s) red[h] += red[h + s]; __syncthreads(); }
    woh[(size_t)row * 128 + h] = f2bf(v / (sqrtf(red[0]) + 1e-30f));
}

// ---- goal_w: split-K partial reduction over W ----
__global__ __launch_bounds__(256)
void k_goalw_part(const float* __restrict__ gw, const float* __restrict__ wes,
                  const float* __restrict__ wupd2, float* __restrict__ part,
                  float* __restrict__ pcnt)
{
    int c = blockIdx.x, b = blockIdx.y;
    int w0 = c * 32;
    __shared__ float sc[32];
    __shared__ float sa[256];
    int tid = threadIdx.x;
    if (tid < 32) sc[tid] = gw[b * Wn + w0 + tid] * wes[b * Wn + w0 + tid];
    __syncthreads();
    if (tid == 0) {
        float n = 0.f;
        for (int w = 0; w < 32; ++w) n += (sc[w] != 0.f) ? 1.f : 0.f;
        pcnt[c * 8 + b] = n;
    }
    int d = tid & 127, h = tid >> 7;
    float acc = 0.f;
    for (int w = h; w < 32; w += 2)
        acc += sc[w] * wupd2[(size_t)(b * Wn + w0 + w) * 128 + d];
    sa[tid] = acc; __syncthreads();
    if (h == 0) part[((size_t)c * 8 + b) * 128 + d] = sa[d] + sa[128 + d];
}

__global__ void k_goalw_fin(const float* __restrict__ part, const float* __restrict__ pcnt,
                            float* __restrict__ goalw)
{
    int b = blockIdx.x, d = threadIdx.x;
    float s = 0.f, n = 0.f;
    for (int c = 0; c < 64; ++c) s += part[((size_t)c * 8 + b) * 128 + d];
    for (int c = 0; c < 64; ++c) n += pcnt[c * 8 + b];
    goalw[b * 128 + d] = s / (n + 1e-30f);
}

__global__ void k_goalnext(const float* __restrict__ goalw, const float* __restrict__ node,
                           const float* __restrict__ Wg, const float* __restrict__ bg,
                           const float* __restrict__ Wu2, const float* __restrict__ bu2,
                           float* __restrict__ outg)
{
    int b = blockIdx.x, h = threadIdx.x;
    float su = bg[h], sf = bu2[h];
    for (int k = 0; k < 128; ++k) {
        float g = goalw[b * 128 + k];
        su += g * Wg[h * 128 + k];
        sf += g * Wu2[h * 256 + k] + node[b * 128 + k] * Wu2[h * 256 + 128 + k];
    }
    float gu = fmaxf(su, 0.f);
    float f = sigm(sf);
    outg[b * 128 + h] = fmaxf(f, FTc) * node[b * 128 + h] + (1.f - f) * gu;
}

__global__ void k_copyspans(const float* __restrict__ wupd, float* __restrict__ out)
{
    int i = blockIdx.x * 256 + threadIdx.x;
    F4 v = ((const F4*)wupd)[i];
    int row = i >> 5;
    int col = i & 31;
    int b = row >> 11, w = row & 2047;
    int dst;
    if (w < Ln) dst = ((b * Ln + w) << 5) + col;
    else        dst = (BLDc >> 2) + ((b * Ln + (w - Ln)) << 5) + col;
    ((F4*)out)[dst] = v;
}

// ---------------- launch ----------------
extern "C" void kernel_launch(void* const* d_in, const int* in_sizes, int n_in,
                              void* d_out, int out_size, void* d_ws, size_t ws_size,
                              hipStream_t stream)
{
    const float* span0 = (const float*)d_in[0];
    const float* span1 = (const float*)d_in[1];
    const float* node  = (const float*)d_in[2];
    const float* opemb = (const float*)d_in[3];
    const float* wes   = (const float*)d_in[4];
    const float* wem   = (const float*)d_in[5];
    const float* wopr  = (const float*)d_in[6];
    const float* ww    = (const float*)d_in[7];
    const float* dep0  = (const float*)d_in[8];
    const float* dep1  = (const float*)d_in[9];
    const float* gw    = (const float*)d_in[10];
    const float* wws_W = (const float*)d_in[11]; const float* wws_b = (const float*)d_in[12];
    const float* wwk_W = (const float*)d_in[13]; const float* wwk_b = (const float*)d_in[14];
    const float* wup_W = (const float*)d_in[15]; const float* wup_b = (const float*)d_in[16];
    const float* gw_W  = (const float*)d_in[17]; const float* gw_b  = (const float*)d_in[18];
    const float* wo_W  = (const float*)d_in[19]; const float* wo_b  = (const float*)d_in[20];
    const float* bf_W  = (const float*)d_in[21]; const float* bf_b  = (const float*)d_in[22];
    const float* bf2_W = (const float*)d_in[23]; const float* bf2_b = (const float*)d_in[24];
    const float* lo_W  = (const float*)d_in[25]; const float* lo_b  = (const float*)d_in[26];
    const float* ow_W  = (const float*)d_in[27]; const float* ow_b  = (const float*)d_in[28];
    const float* wg_W  = (const float*)d_in[29]; const float* wg_b  = (const float*)d_in[30];
    const float* u2b_W = (const float*)d_in[31]; const float* u2b_b = (const float*)d_in[32];
    const float* wof_W = (const float*)d_in[33]; const float* wof_b = (const float*)d_in[34];
    const float* wor_W = (const float*)d_in[35]; const float* wor_b = (const float*)d_in[36];
    const float* wou_W = (const float*)d_in[37]; const float* wou_b = (const float*)d_in[38];

    float* out = (float*)d_out;
    float* out_op   = out + 2 * BLDc;
    float* out_goal = out + 2 * BLDc + Bn * Pn * Dn;

    float* ws = (float*)d_ws;
    float* allword = ws;                  // BWD f32 (pass-1 ACT3 base; dead in pass 2)
    float* wupd    = ws + 1 * BWDc;       // BWD f32 (output span source)
    float* tmpA    = ws + 2 * BWDc;       // BWD f32
    float* tmpB    = ws + 3 * BWDc;       // BWD f32
    float* sm      = ws + 4 * BWDc;       // small block (458752 f32)
    float* gvec   = sm;
    float* gnorm  = sm + 1024;
    float* wordop = sm + 1056;
    float* opembN = sm + 9248;
    float* opn    = sm + 17440;
    float* cf     = sm + 25632;
    float* crel   = sm + 25696;
    float* opw    = sm + 25760;
    float* goalw  = sm + 33952;
    float* fgb    = sm + 34976;
    float* relb   = sm + 166048;
    float* wopn   = sm + 297120;

    short* allwordh = (short*)(ws + 4 * (size_t)BWDc + 458752);
    short* wupdh  = allwordh + BWDc;
    short* wordgh = wupdh + BWDc;        // word_g, later word_o
    short* wwkh   = wordgh + BWDc;
    short* wwsh   = wwkh + BWDc;
    short* Xblk   = wwsh + BWDc;                         // blocked Xk (4 MB)
    short* Awwem  = Xblk + BWDc;                         // 8*2048*2048 bf16
    short* dep0b  = Awwem + (size_t)Bn * Wn * Wn;        // 8*1024*1024 bf16
    short* dep1b  = dep0b + (size_t)Bn * Ln * Ln;

    // scratch aliases (stream-order verified):
    short* XblkS1 = (short*)tmpA;    // pass-1 Xs (4MB); tmpA dead until wo-lin
    short* pWW1   = dep0b;           // z=4: 4*8*2048*128*2B = 16.78MB = dep0b+dep1b; fin before dep WRA
    short* pDep1  = (short*)tmpB;    // z=4: 4*8*1024*128*2B = 8.39MB = tmpB; tmpB dead until forget
    short* XblkS2 = (short*)allword; // pass-2 Xs; allword dead in pass 2
    short* pWW2   = (short*)tmpA;    // 16.78MB spans tmpA+tmpB; both free at pass-2 start
    short* pDep2  = (short*)tmpB;    // reused after WW2 fin (stream-ordered)

    const dim3 blk(256);

    // --- pass 1 ---
    k_allword<<<1024, blk, 0, stream>>>(span0, span1, allword, allwordh);
    // Xk + Xs in one pass over allword
    lin2x<<<512, blk, 0, stream>>>(allwordh, wwk_W, wwk_b, wws_W, wws_b, Xblk, XblkS1);
    // word_w_k = l2((ww*wem) @ Xk); bf16 A write-through; barrier-free split-K
    mfma_gemm6<1,true><<<dim3(32, 8, 4), blk, 0, stream>>>(ww, wem, nullptr, Awwem,
        Xblk, pWW1, Wn, Wn, 512, 0);
    k_gemm_finh<<<16384, 128, 0, stream>>>(pWW1, wwkh, Wn, 4, Wn, 0);
    // word_w_s halves; bf16 dep write-through
    mfma_gemm6<0,true><<<dim3(16, 8, 4), blk, 0, stream>>>(dep0, nullptr, nullptr, dep0b,
        XblkS1, pDep1, Ln, Ln, 256, 0);
    k_gemm_finh<<<8192, 128, 0, stream>>>(pDep1, wwsh, Ln, 4, Wn, 0);
    mfma_gemm6<0,true><<<dim3(16, 8, 4), blk, 0, stream>>>(dep1, nullptr, nullptr, dep1b,
        XblkS1, pDep1, Ln, Ln, 256, 32);
    k_gemm_finh<<<8192, 128, 0, stream>>>(pDep1, wwsh, Ln, 4, Wn, Ln);
    // word_g
    k_goalg<<<8, 128, 0, stream>>>(node, gw_W, gw_b, gvec, gnorm);
    k_wordg<<<16384, 128, 0, stream>>>(gvec, gnorm, gw, wordgh);
    // forget = sigmoid(lin(concat(all_word, word_g, word_w_k, word_w_s)))
    linmfma<4,2,1,16><<<1024, blk, 0, stream>>>(allwordh, wordgh, wwkh, wwsh,
        bf_W, bf_b, tmpB, nullptr, IDM, 0, 0, IDM, 0, 0, nullptr, nullptr);
    // word_updated (f32 + bf16)
    linmfma<3,3,3,16><<<1024, blk, 0, stream>>>(wordgh, wwkh, wwsh, nullptr,
        wup_W, wup_b, wupd, wupdh, IDM, 0, 0, IDM, 0, 0, tmpB, allword);
    // Y = lin(word_updated, w_o)
    linmfma<1,0,1,16><<<1024, blk, 0, stream>>>(wupdh, nullptr, nullptr, nullptr,
        wo_W, wo_b, tmpA, nullptr, IDM, 0, 0, IDM, 0, 0, nullptr, nullptr);
    // word_op (split-K; tmpB dead)
    k_wordop_part<<<dim3(64, 8), blk, 0, stream>>>(wes, wopr, tmpA, tmpB, tmpB + 524288);
    k_wordop_fin<<<64, 128, 0, stream>>>(tmpB, tmpB + 524288, wordop);
    k_opemb<<<64, 128, 0, stream>>>(opemb, wordop, bf2_W, bf2_b, lo_W, lo_b, opembN, out_op);
    k_opn<<<64, 128, 0, stream>>>(opembN, opn);
    k_cfrel<<<64, blk, 0, stream>>>(opn, wof_W, wof_b, wor_W, wor_b, cf, crel);
    k_fgrel<<<512, blk, 0, stream>>>(wupd, wof_W, wor_W, cf, crel, fgb, relb);
    k_wopnew<<<64, blk, 0, stream>>>(wopr, fgb, relb, wou_W, wou_b, wopn);
    k_opw<<<64, 128, 0, stream>>>(opembN, ow_W, ow_b, opw);
    k_wordo<<<16384, 128, 0, stream>>>(wopn, opw, wordgh);   // wordgh now = word_o

    // --- pass 2 ---
    lin2x<<<512, blk, 0, stream>>>(wupdh, wwk_W, wwk_b, wws_W, wws_b, Xblk, XblkS2);
    mfma_gemm6<2,false><<<dim3(32, 8, 4), blk, 0, stream>>>(nullptr, nullptr, Awwem, nullptr,
        Xblk, pWW2, Wn, Wn, 512, 0);
    k_gemm_finh<<<16384, 128, 0, stream>>>(pWW2, wwkh, Wn, 4, Wn, 0);
    mfma_gemm6<2,false><<<dim3(16, 8, 4), blk, 0, stream>>>(nullptr, nullptr, dep0b, nullptr,
        XblkS2, pDep2, Ln, Ln, 256, 0);
    k_gemm_finh<<<8192, 128, 0, stream>>>(pDep2, wwsh, Ln, 4, Wn, 0);
    mfma_gemm6<2,false><<<dim3(16, 8, 4), blk, 0, stream>>>(nullptr, nullptr, dep1b, nullptr,
        XblkS2, pDep2, Ln, Ln, 256, 32);
    k_gemm_finh<<<8192, 128, 0, stream>>>(pDep2, wwsh, Ln, 4, Wn, Ln);
    // word_updated2 = relu(lin(concat(word_o, word_w_k2, word_w_s2)))
    linmfma<3,1,1,16><<<1024, blk, 0, stream>>>(wordgh, wwkh, wwsh, nullptr,
        wup_W, wup_b, tmpA, nullptr, IDM, 0, 0, IDM, 0, 0, nullptr, nullptr);
    // goal path (split-K; tmpB dead)
    k_goalw_part<<<dim3(64, 8), blk, 0, stream>>>(gw, wes, tmpA, tmpB, tmpB + 65536);
    k_goalw_fin<<<8, 128, 0, stream>>>(tmpB, tmpB + 65536, goalw);
    k_goalnext<<<8, 128, 0, stream>>>(goalw, node, wg_W, wg_b, u2b_W, u2b_b, out_goal);
    k_copyspans<<<2048, blk, 0, stream>>>(wupd, out);
}

// Round 12
// 339.078 us; speedup vs baseline: 1.3112x; 1.3112x over previous
//
#include <hip/hip_runtime.h>

// ---------------- problem constants ----------------
constexpr int Bn = 8, Ln = 1024, Dn = 128, Pn = 8, Wn = 2048;
constexpr float FTc = 0.1f;
constexpr int BLDc = Bn * Ln * Dn;   // 1048576
constexpr int BWDc = Bn * Wn * Dn;   // 2097152
constexpr int IDM = 1 << 28;         // identity row-map modulus

struct __align__(16) F4 { float v[4]; };

typedef __attribute__((ext_vector_type(8))) __bf16 bf16x8;
typedef __attribute__((ext_vector_type(8))) short short8v;
typedef __attribute__((ext_vector_type(4))) short short4v;
typedef __attribute__((ext_vector_type(4))) float f32x4;

static __device__ __forceinline__ float sigm(float x) { return 1.f / (1.f + expf(-x)); }

// f32 -> bf16 bits, round-to-nearest-even
static __device__ __forceinline__ short f2bf(float f) {
    unsigned u = __builtin_bit_cast(unsigned, f);
    unsigned r = (u + 0x7FFFu + ((u >> 16) & 1u)) >> 16;
    return (short)r;
}

// ---------------- MFMA linear:  Y = act( X @ W^T + b ) ----------------
// X: concat of NSRC bf16 row-major sources (128 cols each), row-mapped.
// OUT bitmask: 1 = f32 Y, 2 = bf16 Yh, 8 = span-mapped f32 outs (ACT3 path).
// ACT: 0 none,1 relu,2 sigmoid,3 forget-update with base read from
//      span0/span1 (bbuf0/bbuf1) via W-space row map.
template<int NSRC, int ACT, int OUT, int BM>
__global__ __launch_bounds__(256)
void linmfma(const short* __restrict__ x0, const short* __restrict__ x1,
             const short* __restrict__ x2, const short* __restrict__ x3,
             const float* __restrict__ Wt, const float* __restrict__ bias,
             float* __restrict__ Y, short* __restrict__ Yh,
             int in_mod, int in_stride, int in_off,
             int out_mod, int out_stride, int out_off,
             const float* __restrict__ fbuf, const float* __restrict__ bbuf0,
             const float* __restrict__ bbuf1, float* __restrict__ outs)
{
    constexpr int K = NSRC * 128;
    constexpr int NKB = K / 64;
    constexpr int WRr = BM / 16;
    constexpr int WC = 4 / WRr;
    constexpr int NF = 8 / WC;
    constexpr int CPW = 128 / WC;
    __shared__ short sX[BM * 72];
    __shared__ short sW[128 * 72];

    const int tid = threadIdx.x;
    const int wave = tid >> 6, lane = tid & 63;
    const int l15 = lane & 15, l4 = lane >> 4;
    const int rg = wave % WRr, cg = wave / WRr;
    const int n0 = blockIdx.x * BM;
    const int inRow0  = (n0 / in_mod)  * in_stride  + (n0 % in_mod)  + in_off;
    const int outRow0 = (n0 / out_mod) * out_stride + (n0 % out_mod) + out_off;

    f32x4 acc[NF];
    #pragma unroll
    for (int nf = 0; nf < NF; ++nf) acc[nf] = (f32x4){0.f, 0.f, 0.f, 0.f};

    const int xrow = tid >> 3, xk8 = (tid & 7) * 8;

    for (int kb = 0; kb < NKB; ++kb) {
        const int k0 = kb * 64;
        __syncthreads();
        if (tid < BM * 8) {
            const short* __restrict__ src;
            { int s = k0 >> 7; src = (s == 0) ? x0 : (s == 1) ? x1 : (s == 2) ? x2 : x3; }
            const int koff = k0 & 127;
            *(short8v*)&sX[xrow * 72 + xk8] =
                *(const short8v*)(src + (size_t)(inRow0 + xrow) * 128 + koff + xk8);
        }
        #pragma unroll
        for (int it = 0; it < 4; ++it) {
            int idx = tid + it * 256;
            int m = idx >> 3, k8 = (idx & 7) * 8;
            const float* pw = Wt + (size_t)m * K + k0 + k8;
            F4 v0 = *(const F4*)pw, v1 = *(const F4*)(pw + 4);
            short8v sv;
            #pragma unroll
            for (int e = 0; e < 4; ++e) { sv[e] = f2bf(v0.v[e]); sv[4 + e] = f2bf(v1.v[e]); }
            *(short8v*)&sW[m * 72 + k8] = sv;
        }
        __syncthreads();
        #pragma unroll
        for (int ksub = 0; ksub < 2; ++ksub) {
            bf16x8 af = *(const bf16x8*)&sX[(rg * 16 + l15) * 72 + ksub * 32 + l4 * 8];
            #pragma unroll
            for (int nf = 0; nf < NF; ++nf) {
                bf16x8 bv = *(const bf16x8*)&sW[(cg * CPW + nf * 16 + l15) * 72 + ksub * 32 + l4 * 8];
                acc[nf] = __builtin_amdgcn_mfma_f32_16x16x32_bf16(af, bv, acc[nf], 0, 0, 0);
            }
        }
    }

    const int r0 = rg * 16 + l4 * 4;
    #pragma unroll
    for (int nf = 0; nf < NF; ++nf) {
        int col = cg * CPW + nf * 16 + l15;
        float bs = bias[col];
        #pragma unroll
        for (int r = 0; r < 4; ++r) {
            int row = outRow0 + r0 + r;
            float v = acc[nf][r] + bs;
            if constexpr (ACT == 1) v = fmaxf(v, 0.f);
            if constexpr (ACT == 2) v = sigm(v);
            if constexpr (ACT == 3) {
                int bw = row & 2047, bb = row >> 11;
                const float* bp = (bw < Ln) ? bbuf0 : bbuf1;
                float base = bp[(size_t)((bb << 10) + (bw & 1023)) * 128 + col];
                float f = fbuf[(size_t)row * 128 + col];
                v = fmaxf(f, FTc) * base + (1.f - f) * fmaxf(v, 0.f);
                if constexpr (OUT & 8) {
                    int drow = (bw < Ln) ? (bb * Ln + bw) : (8192 + bb * Ln + (bw - Ln));
                    outs[(size_t)drow * 128 + col] = v;
                }
            }
            if constexpr (OUT & 1) Y[(size_t)row * 128 + col] = v;
            if constexpr (OUT & 2) Yh[(size_t)row * 128 + col] = f2bf(v);
        }
    }
}

// ---------------- dual-output X producer ----------------
// Xk = x @ W0^T + b0, Xs = x @ W1^T + b1; both in blocked bf16 layout
// (chunk b*64+kb32 = [col 0..127][kin 0..31], 4096 shorts). Identity row map.
__global__ __launch_bounds__(256)
void lin2x(const short* __restrict__ x0,
           const float* __restrict__ W0, const float* __restrict__ b0v,
           const float* __restrict__ W1, const float* __restrict__ b1v,
           short* __restrict__ Xout0, short* __restrict__ Xout1)
{
    __shared__ short sX[32 * 72];
    __shared__ short sW[2][128 * 72];
    const int tid = threadIdx.x;
    const int wave = tid >> 6, lane = tid & 63;
    const int l15 = lane & 15, l4 = lane >> 4;
    const int rg = wave & 1, cg = wave >> 1;
    const int n0 = blockIdx.x * 32;

    f32x4 acc[2][4];
    #pragma unroll
    for (int o = 0; o < 2; ++o) {
        #pragma unroll
        for (int nf = 0; nf < 4; ++nf) {
            acc[o][nf] = (f32x4){0.f, 0.f, 0.f, 0.f};
        }
    }

    const int xrow = tid >> 3, xk8 = (tid & 7) * 8;

    #pragma unroll
    for (int kb = 0; kb < 2; ++kb) {
        const int k0 = kb * 64;
        __syncthreads();
        *(short8v*)&sX[xrow * 72 + xk8] =
            *(const short8v*)(x0 + (size_t)(n0 + xrow) * 128 + k0 + xk8);
        #pragma unroll
        for (int o = 0; o < 2; ++o) {
            const float* __restrict__ Wt = o ? W1 : W0;
            #pragma unroll
            for (int it = 0; it < 4; ++it) {
                int idx = tid + it * 256;
                int m = idx >> 3, k8 = (idx & 7) * 8;
                const float* pw = Wt + (size_t)m * 128 + k0 + k8;
                F4 v0 = *(const F4*)pw, v1 = *(const F4*)(pw + 4);
                short8v sv;
                #pragma unroll
                for (int e = 0; e < 4; ++e) { sv[e] = f2bf(v0.v[e]); sv[4 + e] = f2bf(v1.v[e]); }
                *(short8v*)&sW[o][m * 72 + k8] = sv;
            }
        }
        __syncthreads();
        #pragma unroll
        for (int ksub = 0; ksub < 2; ++ksub) {
            bf16x8 af = *(const bf16x8*)&sX[(rg * 16 + l15) * 72 + ksub * 32 + l4 * 8];
            #pragma unroll
            for (int o = 0; o < 2; ++o) {
                #pragma unroll
                for (int nf = 0; nf < 4; ++nf) {
                    bf16x8 bv = *(const bf16x8*)&sW[o][(cg * 64 + nf * 16 + l15) * 72 + ksub * 32 + l4 * 8];
                    acc[o][nf] = __builtin_amdgcn_mfma_f32_16x16x32_bf16(af, bv, acc[o][nf], 0, 0, 0);
                }
            }
        }
    }

    const int r0 = rg * 16 + l4 * 4;
    __syncthreads();
    #pragma unroll
    for (int o = 0; o < 2; ++o) {
        const float* bv = o ? b1v : b0v;
        #pragma unroll
        for (int nf = 0; nf < 4; ++nf) {
            int col = cg * 64 + nf * 16 + l15;
            float bs = bv[col];
            #pragma unroll
            for (int r = 0; r < 4; ++r) {
                sW[o][col * 40 + r0 + r] = f2bf(acc[o][nf][r] + bs);
            }
        }
    }
    __syncthreads();
    const int bb = n0 >> 11, kbo = (n0 & 2047) >> 5;
    #pragma unroll
    for (int o = 0; o < 2; ++o) {
        short* __restrict__ dst = (o ? Xout1 : Xout0) + ((size_t)(bb * 64 + kbo)) * 4096;
        #pragma unroll
        for (int it = 0; it < 2; ++it) {
            int t2 = tid + it * 256;
            int col = t2 >> 2, k8 = (t2 & 3) * 8;
            *(short8v*)(dst + (size_t)t2 * 8) = *(const short8v*)&sW[o][col * 40 + k8];
        }
    }
}

// ---------------- MFMA gemm (512 thr, dual K-group):  Yh = l2( A @ X ) ------
// nrm() dropped: positive per-row scale cancels under row-l2.
// AMODE: 0 = A0 f32; 1 = A0*A1 f32 inline; 2 = Abf bf16 row-major.
// WRA: write bf16-converted A through to Awr (row-major) for pass-2 reuse.
// 8 waves: kg = wave>>2 handles K-half; sub-waves tile BM x 128 output.
template<int AMODE, int BM, bool WRA>
__global__ __launch_bounds__(512)
void mfma_gemm2(const float* __restrict__ A0, const float* __restrict__ A1,
                const short* __restrict__ Abf, short* __restrict__ Awr,
                const short* __restrict__ Xblk, short* __restrict__ Yh,
                int NI, int KJ, int xkb0, int ybs, int yoff)
{
    constexpr int WR = BM / 16;
    constexpr int WC = 4 / WR;
    constexpr int NF = 8 / WC;
    constexpr int CPW = 128 / WC;
    __shared__ short sA[2][BM * 72];
    __shared__ short sB[2][128 * 72];
    __shared__ float srow[WC][BM];

    const int tid = threadIdx.x;
    const int wave = tid >> 6, lane = tid & 63;
    const int l15 = lane & 15, l4 = lane >> 4;
    const int kg = wave >> 2;
    const int sub = wave & 3;
    const int rg = (WR == 2) ? (sub >> 1) : 0;
    const int cg = (WR == 2) ? (sub & 1) : sub;
    const int half = tid >> 8;
    const int th = tid & 255;
    const int b = blockIdx.y;
    const int i0 = blockIdx.x * BM;
    const size_t aBase = ((size_t)b * NI + i0) * KJ;
    const int KH = KJ >> 1;
    const int nkb = KH >> 6;
    const int kofs = half * KH;
    const int cbase = b * 64 + xkb0 + half * (KH >> 5);

    const int arow = th >> 3, ak16 = (th & 7) * 8, ak8 = (th & 3) * 8;

    f32x4 acc[NF];
    #pragma unroll
    for (int nf = 0; nf < NF; ++nf) acc[nf] = (f32x4){0.f, 0.f, 0.f, 0.f};

    short8v ra;
    F4 rav0, rav1, raw0, raw1;
    short8v rb0, rb1, rb2, rb3;

#define LOADA(KB)                                                              \
    if (th < BM * 8) {                                                         \
        size_t aoff = aBase + (size_t)arow * KJ + kofs + (KB)*64 + ak16;       \
        if constexpr (AMODE == 2) {                                            \
            ra = *(const short8v*)(Abf + aoff);                                \
        } else {                                                               \
            rav0 = *(const F4*)(A0 + aoff); rav1 = *(const F4*)(A0 + aoff + 4);\
            if constexpr (AMODE == 1) {                                        \
                raw0 = *(const F4*)(A1 + aoff); raw1 = *(const F4*)(A1 + aoff + 4); \
            }                                                                  \
        }                                                                      \
    }
#define STOREA(KB)                                                             \
    if (th < BM * 8) {                                                         \
        short8v sv;                                                            \
        if constexpr (AMODE == 2) { sv = ra; }                                 \
        else {                                                                 \
            _Pragma("unroll")                                                  \
            for (int e = 0; e < 4; ++e) {                                      \
                float f0 = rav0.v[e], f1 = rav1.v[e];                          \
                if constexpr (AMODE == 1) { f0 *= raw0.v[e]; f1 *= raw1.v[e]; }\
                sv[e] = f2bf(f0); sv[4 + e] = f2bf(f1);                        \
            }                                                                  \
        }                                                                      \
        *(short8v*)&sA[half][arow * 72 + ak16] = sv;                           \
        if constexpr (WRA)                                                     \
            *(short8v*)(Awr + aBase + (size_t)arow * KJ + kofs + (KB)*64 + ak16) = sv; \
    }
#define LOADB(KB)                                                              \
    {                                                                          \
        const short* s0 = Xblk + ((size_t)(cbase + (KB)*2)) * 4096;            \
        rb0 = *(const short8v*)(s0 + (size_t)th * 8);                          \
        rb1 = *(const short8v*)(s0 + (size_t)(th + 256) * 8);                  \
        rb2 = *(const short8v*)(s0 + 4096 + (size_t)th * 8);                   \
        rb3 = *(const short8v*)(s0 + 4096 + (size_t)(th + 256) * 8);           \
    }
#define STOREB()                                                               \
    {                                                                          \
        int c0 = th >> 2;             int c1 = (th + 256) >> 2;                \
        *(short8v*)&sB[half][c0 * 72 + ak8]      = rb0;                        \
        *(short8v*)&sB[half][c1 * 72 + ak8]      = rb1;                        \
        *(short8v*)&sB[half][c0 * 72 + 32 + ak8] = rb2;                        \
        *(short8v*)&sB[half][c1 * 72 + 32 + ak8] = rb3;                        \
    }

    LOADA(0); LOADB(0);
    STOREA(0); STOREB();
    __syncthreads();

    for (int kb = 0; kb < nkb; ++kb) {
        const bool more = (kb + 1 < nkb);
        if (more) { LOADA(kb + 1); LOADB(kb + 1); }
        #pragma unroll
        for (int ksub = 0; ksub < 2; ++ksub) {
            bf16x8 af = *(const bf16x8*)&sA[kg][(rg * 16 + l15) * 72 + ksub * 32 + l4 * 8];
            #pragma unroll
            for (int nf = 0; nf < NF; ++nf) {
                bf16x8 bv = *(const bf16x8*)&sB[kg][(cg * CPW + nf * 16 + l15) * 72 + ksub * 32 + l4 * 8];
                acc[nf] = __builtin_amdgcn_mfma_f32_16x16x32_bf16(af, bv, acc[nf], 0, 0, 0);
            }
        }
        if (more) {
            __syncthreads();
            STOREA(kb + 1); STOREB();
            __syncthreads();
        }
    }
#undef LOADA
#undef STOREA
#undef LOADB
#undef STOREB

    // combine kg=1 into kg=0 via LDS (reuse sB as f32, stride 132)
    float* sC = (float*)&sB[0][0];
    __syncthreads();
    if (kg == 1) {
        #pragma unroll
        for (int nf = 0; nf < NF; ++nf) {
            #pragma unroll
            for (int r = 0; r < 4; ++r) {
                sC[(rg * 16 + l4 * 4 + r) * 132 + cg * CPW + nf * 16 + l15] = acc[nf][r];
            }
        }
    }
    __syncthreads();
    float s[4];
    if (kg == 0) {
        #pragma unroll
        for (int nf = 0; nf < NF; ++nf) {
            #pragma unroll
            for (int r = 0; r < 4; ++r) {
                acc[nf][r] += sC[(rg * 16 + l4 * 4 + r) * 132 + cg * CPW + nf * 16 + l15];
            }
        }
        #pragma unroll
        for (int r = 0; r < 4; ++r) {
            float t = 0.f;
            #pragma unroll
            for (int nf = 0; nf < NF; ++nf) t += acc[nf][r] * acc[nf][r];
            t += __shfl_xor(t, 1); t += __shfl_xor(t, 2);
            t += __shfl_xor(t, 4); t += __shfl_xor(t, 8);
            s[r] = t;
        }
        if (l15 == 0) {
            #pragma unroll
            for (int r = 0; r < 4; ++r) srow[cg][rg * 16 + l4 * 4 + r] = s[r];
        }
    }
    __syncthreads();
    if (kg == 0) {
        const int rbase = b * ybs + yoff + i0 + rg * 16 + l4 * 4;
        #pragma unroll
        for (int r = 0; r < 4; ++r) {
            float tot = 0.f;
            #pragma unroll
            for (int c = 0; c < WC; ++c) tot += srow[c][rg * 16 + l4 * 4 + r];
            float inv = 1.f / (sqrtf(tot) + 1e-30f);
            #pragma unroll
            for (int nf = 0; nf < NF; ++nf) {
                Yh[(size_t)(rbase + r) * 128 + cg * CPW + nf * 16 + l15] = f2bf(acc[nf][r] * inv);
            }
        }
    }
}

// ---------------- small kernels ----------------
__global__ void k_allwordh(const float* __restrict__ s0, const float* __restrict__ s1,
                           short* __restrict__ awh)
{
    int i = blockIdx.x * 256 + threadIdx.x;
    int b = i / (Ln * Dn / 4);
    F4 v0 = ((const F4*)s0)[i];
    F4 v1 = ((const F4*)s1)[i];
    int d0 = i + b * (Ln * Dn / 4);
    int d1 = i + (b + 1) * (Ln * Dn / 4);
    short4v h0, h1;
    #pragma unroll
    for (int e = 0; e < 4; ++e) { h0[e] = f2bf(v0.v[e]); h1[e] = f2bf(v1.v[e]); }
    ((short4v*)awh)[d0] = h0;
    ((short4v*)awh)[d1] = h1;
}

__global__ void k_goalg(const float* __restrict__ node, const float* __restrict__ Wg,
                        const float* __restrict__ bg, float* __restrict__ gvec,
                        float* __restrict__ gnorm)
{
    int b = blockIdx.x, h = threadIdx.x;
    float s = bg[h];
    for (int k = 0; k < 128; ++k) s += node[b * 128 + k] * Wg[h * 128 + k];
    gvec[b * 128 + h] = s;
    __shared__ float red[128];
    red[h] = s * s; __syncthreads();
    for (int st = 64; st > 0; st >>= 1) { if (h < st) red[h] += red[h + st]; __syncthreads(); }
    if (h == 0) gnorm[b] = sqrtf(red[0]);
}

__global__ void k_wordg(const float* __restrict__ gvec, const float* __restrict__ gnorm,
                        const float* __restrict__ gw, short* __restrict__ wgh)
{
    int row = blockIdx.x; int b = row >> 11; int h = threadIdx.x;
    float s = gw[row];
    float coef = s / (s * gnorm[b] + 1e-30f);
    wgh[(size_t)row * 128 + h] = f2bf(gvec[b * 128 + h] * coef);
}

// ---- word_op: split-K partial reduction over W ----
__global__ __launch_bounds__(256)
void k_wordop_part(const float* __restrict__ wes, const float* __restrict__ wopr,
                   const float* __restrict__ Yl, float* __restrict__ part,
                   float* __restrict__ pcnt)
{
    int c = blockIdx.x, b = blockIdx.y;
    int w0 = c * 32;
    __shared__ float sc[32][8];
    int tid = threadIdx.x;
    {
        int w = tid >> 3, p = tid & 7;
        sc[w][p] = wes[b * Wn + w0 + w] * wopr[(size_t)(b * Wn + w0 + w) * Pn + p];
    }
    __syncthreads();
    if (tid < 8) {
        float n = 0.f;
        for (int w = 0; w < 32; ++w) n += (sc[w][tid] != 0.f) ? 1.f : 0.f;
        pcnt[(c * 8 + b) * 8 + tid] = n;
    }
    int d = tid & 127, g = tid >> 7;
    float acc[4] = {};
    for (int w = 0; w < 32; ++w) {
        float y = Yl[(size_t)(b * Wn + w0 + w) * 128 + d];
        #pragma unroll
        for (int q = 0; q < 4; ++q) acc[q] += sc[w][g * 4 + q] * y;
    }
    #pragma unroll
    for (int q = 0; q < 4; ++q)
        part[(((size_t)c * 8 + b) * 8 + g * 4 + q) * 128 + d] = acc[q];
}

__global__ void k_wordop_fin(const float* __restrict__ part, const float* __restrict__ pcnt,
                             float* __restrict__ outp)
{
    int bp = blockIdx.x;
    int b = bp >> 3, p = bp & 7;
    int d = threadIdx.x;
    float s = 0.f, n = 0.f;
    for (int c = 0; c < 64; ++c) s += part[(((size_t)c * 8 + b) * 8 + p) * 128 + d];
    for (int c = 0; c < 64; ++c) n += pcnt[(c * 8 + b) * 8 + p];
    outp[(size_t)bp * 128 + d] = s / (n + 1e-30f);
}

__global__ void k_opemb(const float* __restrict__ oein, const float* __restrict__ wop,
                        const float* __restrict__ W2, const float* __restrict__ b2,
                        const float* __restrict__ Wlo, const float* __restrict__ blo,
                        float* __restrict__ opembN, float* __restrict__ out2)
{
    int bp = blockIdx.x; int h = threadIdx.x;
    const float* oe = oein + (size_t)bp * 128;
    const float* wo = wop + (size_t)bp * 128;
    float s = b2[h], lo = blo[h];
    for (int k = 0; k < 128; ++k) {
        s += oe[k] * W2[h * 256 + k];
        s += wo[k] * W2[h * 256 + 128 + k];
        lo += wo[k] * Wlo[h * 128 + k];
    }
    float f = sigm(s);
    float v = fmaxf(f, FTc) * oe[h] + (1.f - f) * fmaxf(lo, 0.f);
    opembN[bp * 128 + h] = v;
    out2[bp * 128 + h] = v;
}

__global__ void k_opn(const float* __restrict__ opembN, float* __restrict__ opn)
{
    __shared__ float red[128];
    int bp = blockIdx.x, h = threadIdx.x;
    float v = opembN[bp * 128 + h];
    red[h] = v * v; __syncthreads();
    for (int s = 64; s > 0; s >>= 1) { if (h < s) red[h] += red[h + s]; __syncthreads(); }
    opn[bp * 128 + h] = v / (sqrtf(red[0]) + 1e-30f);
}

__global__ void k_cfrel(const float* __restrict__ opn, const float* __restrict__ Wf,
                        const float* __restrict__ bf, const float* __restrict__ Wr,
                        const float* __restrict__ br, float* __restrict__ cf,
                        float* __restrict__ crel)
{
    int bp = blockIdx.x; int b = bp >> 3, p = bp & 7;
    int t = threadIdx.x;
    float sf = 0.f, sr = 0.f;
    for (int k = t; k < 1024; k += 256) {
        float o = opn[b * 1024 + k];
        sf += o * Wf[p * 1152 + 128 + k];
        sr += o * Wr[p * 1152 + 128 + k];
    }
    __shared__ float rf[256], rr[256];
    rf[t] = sf; rr[t] = sr; __syncthreads();
    for (int s = 128; s > 0; s >>= 1) {
        if (t < s) { rf[t] += rf[t + s]; rr[t] += rr[t + s]; }
        __syncthreads();
    }
    if (t == 0) { cf[bp] = rf[0] + bf[p]; crel[bp] = rr[0] + br[p]; }
}

__global__ __launch_bounds__(256)
void k_fgrel(const float* __restrict__ wupd, const float* __restrict__ Wf,
             const float* __restrict__ Wr, const float* __restrict__ cf,
             const float* __restrict__ crel, float* __restrict__ fgb,
             float* __restrict__ relb)
{
    __shared__ float sXr[32 * 132];
    __shared__ float sinv[32];
    int tid = threadIdx.x;
    int n0 = blockIdx.x * 32;
    for (int l = tid; l < 4096; l += 256) {
        int r = l >> 7, h = l & 127;
        sXr[r * 132 + h] = wupd[(size_t)(n0 + r) * 128 + h];
    }
    __syncthreads();
    if (tid < 32) {
        float s = 0.f;
        for (int h = 0; h < 128; ++h) { float v = sXr[tid * 132 + h]; s += v * v; }
        sinv[tid] = 1.f / (sqrtf(s) + 1e-30f);
    }
    __syncthreads();
    int r = tid >> 3, p = tid & 7;
    int n = n0 + r; int b = n >> 11;
    float af = 0.f, ar = 0.f, inv = sinv[r];
    for (int d = 0; d < 128; ++d) {
        float x = sXr[r * 132 + d] * inv;
        af += x * Wf[p * 1152 + d];
        ar += x * Wr[p * 1152 + d];
    }
    float f = sigm(af + cf[b * 8 + p]);
    fgb[(size_t)n * 8 + p] = fmaxf(f, FTc);
    relb[(size_t)n * 8 + p] = ar + crel[b * 8 + p];
}

__global__ void k_wopnew(const float* __restrict__ wopr, const float* __restrict__ fgb,
                         const float* __restrict__ relb, const float* __restrict__ Wu,
                         const float* __restrict__ bu, float* __restrict__ wopn)
{
    int row = blockIdx.x * 256 + threadIdx.x;
    float t16[16];
    #pragma unroll
    for (int p = 0; p < 8; ++p) t16[p] = wopr[(size_t)row * 8 + p];
    #pragma unroll
    for (int p = 0; p < 8; ++p) t16[8 + p] = relb[(size_t)row * 8 + p];
    float u[8]; float m = -1e30f;
    #pragma unroll
    for (int p = 0; p < 8; ++p) {
        float s = bu[p];
        #pragma unroll
        for (int q = 0; q < 16; ++q) s += Wu[p * 16 + q] * t16[q];
        s = fmaxf(s, 0.f); u[p] = s; m = fmaxf(m, s);
    }
    float tot = 0.f;
    #pragma unroll
    for (int p = 0; p < 8; ++p) { u[p] = expf(u[p] - m); tot += u[p]; }
    float itot = 1.f / tot;
    #pragma unroll
    for (int p = 0; p < 8; ++p) {
        float f = fgb[(size_t)row * 8 + p];
        wopn[(size_t)row * 8 + p] = f * t16[p] + (1.f - f) * u[p] * itot;
    }
}

__global__ void k_opw(const float* __restrict__ opembN, const float* __restrict__ Wo,
                      const float* __restrict__ bo, float* __restrict__ opw)
{
    int bp = blockIdx.x, h = threadIdx.x;
    float s = bo[h];
    for (int d = 0; d < 128; ++d) s += opembN[bp * 128 + d] * Wo[h * 128 + d];
    opw[bp * 128 + h] = s;
}

__global__ void k_wordo(const float* __restrict__ wopn, const float* __restrict__ opw,
                        short* __restrict__ woh)
{
    int row = blockIdx.x; int b = row >> 11; int h = threadIdx.x;
    float c[8];
    #pragma unroll
    for (int p = 0; p < 8; ++p) c[p] = wopn[(size_t)row * 8 + p];
    float v = 0.f;
    #pragma unroll
    for (int p = 0; p < 8; ++p) v += c[p] * opw[(b * 8 + p) * 128 + h];
    __shared__ float red[128];
    red[h] = v * v; __syncthreads();
    for (int s = 64; s > 0; s >>= 1) { if (h < s) red[h] += red[h + s]; __syncthreads(); }
    woh[(size_t)row * 128 + h] = f2bf(v / (sqrtf(red[0]) + 1e-30f));
}

// ---- goal_w: split-K partial reduction over W ----
__global__ __launch_bounds__(256)
void k_goalw_part(const float* __restrict__ gw, const float* __restrict__ wes,
                  const float* __restrict__ wupd2, float* __restrict__ part,
                  float* __restrict__ pcnt)
{
    int c = blockIdx.x, b = blockIdx.y;
    int w0 = c * 32;
    __shared__ float sc[32];
    __shared__ float sa[256];
    int tid = threadIdx.x;
    if (tid < 32) sc[tid] = gw[b * Wn + w0 + tid] * wes[b * Wn + w0 + tid];
    __syncthreads();
    if (tid == 0) {
        float n = 0.f;
        for (int w = 0; w < 32; ++w) n += (sc[w] != 0.f) ? 1.f : 0.f;
        pcnt[c * 8 + b] = n;
    }
    int d = tid & 127, h = tid >> 7;
    float acc = 0.f;
    for (int w = h; w < 32; w += 2)
        acc += sc[w] * wupd2[(size_t)(b * Wn + w0 + w) * 128 + d];
    sa[tid] = acc; __syncthreads();
    if (h == 0) part[((size_t)c * 8 + b) * 128 + d] = sa[d] + sa[128 + d];
}

__global__ void k_goalw_fin(const float* __restrict__ part, const float* __restrict__ pcnt,
                            float* __restrict__ goalw)
{
    int b = blockIdx.x, d = threadIdx.x;
    float s = 0.f, n = 0.f;
    for (int c = 0; c < 64; ++c) s += part[((size_t)c * 8 + b) * 128 + d];
    for (int c = 0; c < 64; ++c) n += pcnt[c * 8 + b];
    goalw[b * 128 + d] = s / (n + 1e-30f);
}

__global__ void k_goalnext(const float* __restrict__ goalw, const float* __restrict__ node,
                           const float* __restrict__ Wg, const float* __restrict__ bg,
                           const float* __restrict__ Wu2, const float* __restrict__ bu2,
                           float* __restrict__ outg)
{
    int b = blockIdx.x, h = threadIdx.x;
    float su = bg[h], sf = bu2[h];
    for (int k = 0; k < 128; ++k) {
        float g = goalw[b * 128 + k];
        su += g * Wg[h * 128 + k];
        sf += g * Wu2[h * 256 + k] + node[b * 128 + k] * Wu2[h * 256 + 128 + k];
    }
    float gu = fmaxf(su, 0.f);
    float f = sigm(sf);
    outg[b * 128 + h] = fmaxf(f, FTc) * node[b * 128 + h] + (1.f - f) * gu;
}

// ---------------- launch ----------------
extern "C" void kernel_launch(void* const* d_in, const int* in_sizes, int n_in,
                              void* d_out, int out_size, void* d_ws, size_t ws_size,
                              hipStream_t stream)
{
    const float* span0 = (const float*)d_in[0];
    const float* span1 = (const float*)d_in[1];
    const float* node  = (const float*)d_in[2];
    const float* opemb = (const float*)d_in[3];
    const float* wes   = (const float*)d_in[4];
    const float* wem   = (const float*)d_in[5];
    const float* wopr  = (const float*)d_in[6];
    const float* ww    = (const float*)d_in[7];
    const float* dep0  = (const float*)d_in[8];
    const float* dep1  = (const float*)d_in[9];
    const float* gw    = (const float*)d_in[10];
    const float* wws_W = (const float*)d_in[11]; const float* wws_b = (const float*)d_in[12];
    const float* wwk_W = (const float*)d_in[13]; const float* wwk_b = (const float*)d_in[14];
    const float* wup_W = (const float*)d_in[15]; const float* wup_b = (const float*)d_in[16];
    const float* gw_W  = (const float*)d_in[17]; const float* gw_b  = (const float*)d_in[18];
    const float* wo_W  = (const float*)d_in[19]; const float* wo_b  = (const float*)d_in[20];
    const float* bf_W  = (const float*)d_in[21]; const float* bf_b  = (const float*)d_in[22];
    const float* bf2_W = (const float*)d_in[23]; const float* bf2_b = (const float*)d_in[24];
    const float* lo_W  = (const float*)d_in[25]; const float* lo_b  = (const float*)d_in[26];
    const float* ow_W  = (const float*)d_in[27]; const float* ow_b  = (const float*)d_in[28];
    const float* wg_W  = (const float*)d_in[29]; const float* wg_b  = (const float*)d_in[30];
    const float* u2b_W = (const float*)d_in[31]; const float* u2b_b = (const float*)d_in[32];
    const float* wof_W = (const float*)d_in[33]; const float* wof_b = (const float*)d_in[34];
    const float* wor_W = (const float*)d_in[35]; const float* wor_b = (const float*)d_in[36];
    const float* wou_W = (const float*)d_in[37]; const float* wou_b = (const float*)d_in[38];

    float* out = (float*)d_out;
    float* out_op   = out + 2 * BLDc;
    float* out_goal = out + 2 * BLDc + Bn * Pn * Dn;

    float* ws = (float*)d_ws;
    float* wupd    = ws;                  // BWD f32 (fgrel input; spans written directly to out)
    float* tmpA    = ws + 1 * BWDc;       // BWD f32
    float* tmpB    = ws + 2 * BWDc;       // BWD f32
    float* sm      = ws + 3 * BWDc;       // small block (458752 f32)
    float* gvec   = sm;
    float* gnorm  = sm + 1024;
    float* wordop = sm + 1056;
    float* opembN = sm + 9248;
    float* opn    = sm + 17440;
    float* cf     = sm + 25632;
    float* crel   = sm + 25696;
    float* opw    = sm + 25760;
    float* goalw  = sm + 33952;
    float* fgb    = sm + 34976;
    float* relb   = sm + 166048;
    float* wopn   = sm + 297120;

    short* allwordh = (short*)(ws + 3 * (size_t)BWDc + 458752);
    short* wupdh  = allwordh + BWDc;
    short* wordgh = wupdh + BWDc;        // word_g, later word_o
    short* wwkh   = wordgh + BWDc;
    short* wwsh   = wwkh + BWDc;
    short* Xblk   = wwsh + BWDc;                         // blocked Xk (4 MB)
    short* Awwem  = Xblk + BWDc;                         // 8*2048*2048 bf16
    short* dep0b  = Awwem + (size_t)Bn * Wn * Wn;        // 8*1024*1024 bf16
    short* dep1b  = dep0b + (size_t)Bn * Ln * Ln;

    // scratch aliases (stream-order verified):
    short* XblkS1 = (short*)tmpA;    // pass-1 Xs (4MB); tmpA next written by wo-lin (after deps)
    short* XblkS2 = (short*)tmpB;    // pass-2 Xs (4MB); tmpB next used by goalw partials (after deps)

    const dim3 blk(256);
    const dim3 blk512(512);

    // --- pass 1 ---
    k_allwordh<<<1024, blk, 0, stream>>>(span0, span1, allwordh);
    // Xk + Xs in one pass over allword
    lin2x<<<512, blk, 0, stream>>>(allwordh, wwk_W, wwk_b, wws_W, wws_b, Xblk, XblkS1);
    // word_w_k = l2((ww*wem) @ Xk); bf16 A write-through
    mfma_gemm2<1,32,true><<<dim3(64, 8), blk512, 0, stream>>>(ww, wem, nullptr, Awwem,
        Xblk, wwkh, Wn, Wn, 0, Wn, 0);
    // word_w_s halves; bf16 dep write-through
    mfma_gemm2<0,16,true><<<dim3(64, 8), blk512, 0, stream>>>(dep0, nullptr, nullptr, dep0b,
        XblkS1, wwsh, Ln, Ln, 0, Wn, 0);
    mfma_gemm2<0,16,true><<<dim3(64, 8), blk512, 0, stream>>>(dep1, nullptr, nullptr, dep1b,
        XblkS1, wwsh, Ln, Ln, 32, Wn, Ln);
    // word_g
    k_goalg<<<8, 128, 0, stream>>>(node, gw_W, gw_b, gvec, gnorm);
    k_wordg<<<16384, 128, 0, stream>>>(gvec, gnorm, gw, wordgh);
    // forget = sigmoid(lin(concat(all_word, word_g, word_w_k, word_w_s)))
    linmfma<4,2,1,16><<<1024, blk, 0, stream>>>(allwordh, wordgh, wwkh, wwsh,
        bf_W, bf_b, tmpB, nullptr, IDM, 0, 0, IDM, 0, 0, nullptr, nullptr, nullptr, nullptr);
    // word_updated: f32 wupd + bf16 wupdh + span outputs (base from span0/span1)
    linmfma<3,3,11,16><<<1024, blk, 0, stream>>>(wordgh, wwkh, wwsh, nullptr,
        wup_W, wup_b, wupd, wupdh, IDM, 0, 0, IDM, 0, 0, tmpB, span0, span1, out);
    // Y = lin(word_updated, w_o)
    linmfma<1,0,1,16><<<1024, blk, 0, stream>>>(wupdh, nullptr, nullptr, nullptr,
        wo_W, wo_b, tmpA, nullptr, IDM, 0, 0, IDM, 0, 0, nullptr, nullptr, nullptr, nullptr);
    // word_op (split-K; tmpB dead after ACT3 consumed forget)
    k_wordop_part<<<dim3(64, 8), blk, 0, stream>>>(wes, wopr, tmpA, tmpB, tmpB + 524288);
    k_wordop_fin<<<64, 128, 0, stream>>>(tmpB, tmpB + 524288, wordop);
    k_opemb<<<64, 128, 0, stream>>>(opemb, wordop, bf2_W, bf2_b, lo_W, lo_b, opembN, out_op);
    k_opn<<<64, 128, 0, stream>>>(opembN, opn);
    k_cfrel<<<64, blk, 0, stream>>>(opn, wof_W, wof_b, wor_W, wor_b, cf, crel);
    k_fgrel<<<512, blk, 0, stream>>>(wupd, wof_W, wor_W, cf, crel, fgb, relb);
    k_wopnew<<<64, blk, 0, stream>>>(wopr, fgb, relb, wou_W, wou_b, wopn);
    k_opw<<<64, 128, 0, stream>>>(opembN, ow_W, ow_b, opw);
    k_wordo<<<16384, 128, 0, stream>>>(wopn, opw, wordgh);   // wordgh now = word_o

    // --- pass 2 ---
    lin2x<<<512, blk, 0, stream>>>(wupdh, wwk_W, wwk_b, wws_W, wws_b, Xblk, XblkS2);
    mfma_gemm2<2,32,false><<<dim3(64, 8), blk512, 0, stream>>>(nullptr, nullptr, Awwem, nullptr,
        Xblk, wwkh, Wn, Wn, 0, Wn, 0);
    mfma_gemm2<2,16,false><<<dim3(64, 8), blk512, 0, stream>>>(nullptr, nullptr, dep0b, nullptr,
        XblkS2, wwsh, Ln, Ln, 0, Wn, 0);
    mfma_gemm2<2,16,false><<<dim3(64, 8), blk512, 0, stream>>>(nullptr, nullptr, dep1b, nullptr,
        XblkS2, wwsh, Ln, Ln, 32, Wn, Ln);
    // word_updated2 = relu(lin(concat(word_o, word_w_k2, word_w_s2)))
    linmfma<3,1,1,16><<<1024, blk, 0, stream>>>(wordgh, wwkh, wwsh, nullptr,
        wup_W, wup_b, tmpA, nullptr, IDM, 0, 0, IDM, 0, 0, nullptr, nullptr, nullptr, nullptr);
    // goal path (split-K; XblkS2 dead)
    k_goalw_part<<<dim3(64, 8), blk, 0, stream>>>(gw, wes, tmpA, tmpB, tmpB + 65536);
    k_goalw_fin<<<8, 128, 0, stream>>>(tmpB, tmpB + 65536, goalw);
    k_goalnext<<<8, 128, 0, stream>>>(goalw, node, wg_W, wg_b, u2b_W, u2b_b, out_goal);
}